// Round 4
// baseline (244.868 us; speedup 1.0000x reference)
//
#include <hip/hip_runtime.h>
#include <math.h>

typedef float f32x4 __attribute__((ext_vector_type(4)));

// Problem constants (from reference setup_inputs)
constexpr int CAP = 262144;      // rows of keys/values
constexpr int NF  = 512;         // in_features == out_features

constexpr int RPW = 32;          // rows per wave in fused kernel
constexpr int NW  = CAP / RPW;   // 8192 waves -> 8192 partial rows
constexpr int GA  = NW / 4;      // 2048 blocks x 4 waves
constexpr int GC  = 128;         // reduction blocks
constexpr int RPC = NW / GC;     // 64 partial rows per reduction block

// ---------------------------------------------------------------------------
// Kernel A (fused, flash-style): one wave owns 32 rows. Per row: read key row
// (2KB/wave) + value row (2KB/wave), L1-distance via shfl butterfly, online
// softmax update of (m, s) and the value accumulator held in registers
// (8 floats/lane = 512/wave). Writes per-wave partials (m_w, s_w, acc_w[512]).
// Reads keys+values exactly once (nontemporal: no reuse).
// ---------------------------------------------------------------------------
__global__ __launch_bounds__(256) void k_fused(
    const float* __restrict__ q, const float* __restrict__ keys,
    const float* __restrict__ vals,
    float* __restrict__ pm, float* __restrict__ ps, float* __restrict__ pacc)
{
    const int lane = threadIdx.x & 63;
    const int wv   = threadIdx.x >> 6;
    const int w    = blockIdx.x * 4 + wv;      // wave id, 0..NW-1

    const f32x4 q0 = *reinterpret_cast<const f32x4*>(q + lane * 8);
    const f32x4 q1 = *reinterpret_cast<const f32x4*>(q + lane * 8 + 4);

    float m = -INFINITY, s = 0.f;
    f32x4 a0 = {0.f, 0.f, 0.f, 0.f};
    f32x4 a1 = {0.f, 0.f, 0.f, 0.f};

    const int row0 = w * RPW;
    #pragma unroll 4
    for (int r = row0; r < row0 + RPW; ++r) {
        const size_t off = (size_t)r * NF + lane * 8;
        // issue all 4 loads up front (64B/lane in flight)
        const f32x4 k0 = __builtin_nontemporal_load(reinterpret_cast<const f32x4*>(keys + off));
        const f32x4 k1 = __builtin_nontemporal_load(reinterpret_cast<const f32x4*>(keys + off + 4));
        const f32x4 v0 = __builtin_nontemporal_load(reinterpret_cast<const f32x4*>(vals + off));
        const f32x4 v1 = __builtin_nontemporal_load(reinterpret_cast<const f32x4*>(vals + off + 4));

        float d = fabsf(k0[0] - q0[0]) + fabsf(k0[1] - q0[1])
                + fabsf(k0[2] - q0[2]) + fabsf(k0[3] - q0[3])
                + fabsf(k1[0] - q1[0]) + fabsf(k1[1] - q1[1])
                + fabsf(k1[2] - q1[2]) + fabsf(k1[3] - q1[3]);
        #pragma unroll
        for (int off2 = 1; off2 < 64; off2 <<= 1) d += __shfl_xor(d, off2, 64);
        const float l = -d;                    // uniform across the wave

        if (l > m) {                           // wave-uniform branch
            const float c = __expf(m - l);     // first iter: exp(-inf)=0
            s = s * c + 1.f;
            a0 = a0 * c + v0;
            a1 = a1 * c + v1;
            m = l;
        } else {
            const float wgt = __expf(l - m);
            s += wgt;
            a0 += wgt * v0;
            a1 += wgt * v1;
        }
    }

    if (lane == 0) { pm[w] = m; ps[w] = s; }
    float* pr = pacc + (size_t)w * NF + lane * 8;
    *reinterpret_cast<f32x4*>(pr)     = a0;
    *reinterpret_cast<f32x4*>(pr + 4) = a1;
}

// ---------------------------------------------------------------------------
// Kernel B: reduce NW partial rows -> GC rows, scaling each by exp(m_w - M).
// M (global max of pm) is recomputed redundantly per block — pure fmax, so
// bit-identical everywhere, and pm (32KB) is L2-resident.
// 256 threads: 128 col-threads (f32x4 => 512 cols) x 2 row-groups.
// ---------------------------------------------------------------------------
__global__ __launch_bounds__(256) void k_red(
    const float* __restrict__ pm, const float* __restrict__ pacc,
    float* __restrict__ part2)
{
    const int tid  = threadIdx.x;
    const int lane = tid & 63;
    const int wv   = tid >> 6;

    // ---- global max M (all threads end with identical M) ----
    float mx = -INFINITY;
    for (int i = tid; i < NW; i += 256) mx = fmaxf(mx, pm[i]);
    #pragma unroll
    for (int off = 1; off < 64; off <<= 1) mx = fmaxf(mx, __shfl_xor(mx, off, 64));
    __shared__ float sm[4];
    if (lane == 0) sm[wv] = mx;
    __syncthreads();
    const float M = fmaxf(fmaxf(sm[0], sm[1]), fmaxf(sm[2], sm[3]));

    // ---- scaled row reduction ----
    const int col = (tid & 127) * 4;
    const int rg  = tid >> 7;
    const int r0  = blockIdx.x * RPC;
    f32x4 acc = {0.f, 0.f, 0.f, 0.f};
    for (int r = r0 + rg; r < r0 + RPC; r += 2) {
        const float sc = __expf(pm[r] - M);
        const f32x4 v = *reinterpret_cast<const f32x4*>(pacc + (size_t)r * NF + col);
        acc += sc * v;
    }

    __shared__ float sp[NF];
    if (rg == 0) *reinterpret_cast<f32x4*>(sp + col) = acc;
    __syncthreads();
    if (rg == 1) {
        sp[col + 0] += acc[0]; sp[col + 1] += acc[1];
        sp[col + 2] += acc[2]; sp[col + 3] += acc[3];
    }
    __syncthreads();
    if (rg == 0)
        *reinterpret_cast<f32x4*>(part2 + (size_t)blockIdx.x * NF + col) =
            *reinterpret_cast<const f32x4*>(sp + col);
}

// ---------------------------------------------------------------------------
// Kernel C: final. Recompute M and S = sum_w s_w * exp(m_w - M) (deterministic,
// identical in both blocks), sum the GC partial rows, normalize, sigmoid.
// ---------------------------------------------------------------------------
__global__ __launch_bounds__(256) void k_final(
    const float* __restrict__ pm, const float* __restrict__ ps,
    const float* __restrict__ part2, float* __restrict__ out)
{
    const int tid  = threadIdx.x;
    const int lane = tid & 63;
    const int wv   = tid >> 6;

    // ---- M ----
    float mx = -INFINITY;
    for (int i = tid; i < NW; i += 256) mx = fmaxf(mx, pm[i]);
    #pragma unroll
    for (int off = 1; off < 64; off <<= 1) mx = fmaxf(mx, __shfl_xor(mx, off, 64));
    __shared__ float sm[4], ss[4];
    if (lane == 0) sm[wv] = mx;
    __syncthreads();
    const float M = fmaxf(fmaxf(sm[0], sm[1]), fmaxf(sm[2], sm[3]));

    // ---- S ----
    float sacc = 0.f;
    for (int i = tid; i < NW; i += 256) sacc += ps[i] * expf(pm[i] - M);
    #pragma unroll
    for (int off = 1; off < 64; off <<= 1) sacc += __shfl_xor(sacc, off, 64);
    if (lane == 0) ss[wv] = sacc;
    __syncthreads();
    const float invS = 1.f / (ss[0] + ss[1] + ss[2] + ss[3]);

    // ---- sum partial rows + sigmoid ----
    const int o = blockIdx.x * 256 + tid;          // grid 2 x 256 = 512
    float acc = 0.f;
    #pragma unroll 8
    for (int j = 0; j < GC; ++j) acc += part2[(size_t)j * NF + o];
    out[o] = 1.f / (1.f + expf(-acc * invS));
}

// ---------------------------------------------------------------------------
extern "C" void kernel_launch(void* const* d_in, const int* in_sizes, int n_in,
                              void* d_out, int out_size, void* d_ws, size_t ws_size,
                              hipStream_t stream)
{
    const float* q    = (const float*)d_in[0];   // [512]
    const float* keys = (const float*)d_in[1];   // [262144, 512]
    const float* vals = (const float*)d_in[2];   // [262144, 512]
    float* out = (float*)d_out;                  // [512]

    // Workspace layout (floats). Total ~16.3 MB.
    float* ws    = (float*)d_ws;
    float* pm    = ws;                           // NW
    float* ps    = pm + NW;                      // NW
    float* pacc  = ps + NW;                      // NW*NF (16 MB), 64KB-aligned
    float* part2 = pacc + (size_t)NW * NF;       // GC*NF (256 KB)

    k_fused<<<GA, 256, 0, stream>>>(q, keys, vals, pm, ps, pacc);
    k_red  <<<GC, 256, 0, stream>>>(pm, pacc, part2);
    k_final<<<2,  256, 0, stream>>>(pm, ps, part2, out);
}

// Round 6
// 198.127 us; speedup vs baseline: 1.2359x; 1.2359x over previous
//
#include <hip/hip_runtime.h>
#include <math.h>

typedef float f32x4 __attribute__((ext_vector_type(4)));

// Problem constants (from reference setup_inputs)
constexpr int CAP = 262144;   // rows of keys/values
constexpr int NF  = 512;      // in_features == out_features

constexpr int G1  = 2048;     // k_logits blocks: 4 waves each -> 8192 waves, 32 rows/wave
constexpr int G3  = 2048;     // k_wsum blocks: 128 rows each
constexpr int G4A = 64;       // k_red blocks: 32 partial-rows each

// ---------------------------------------------------------------------------
// Kernel 1: logits[r] = -sum_f |keys[r,f] - q[f]|  + per-block softmax
// partials (m_b, s_b). One wave per 32 rows, processed in batches of 8 with a
// BATCHED butterfly: 10 shfls / 8 rows instead of 6 / row.
// NOTE: after the butterfly, lanes l, l+8, ..., l+56 hold IDENTICAL logits of
// row (l&7), so the per-lane (m,s) state is replicated 8x across lane groups;
// the wave-combined s must be scaled by 1/8 (exact, power of two).
// ---------------------------------------------------------------------------
__global__ __launch_bounds__(256) void k_logits(
    const float* __restrict__ q, const float* __restrict__ keys,
    float* __restrict__ logits, float* __restrict__ pm, float* __restrict__ ps)
{
    const int tid  = threadIdx.x;
    const int lane = tid & 63;
    const int wv   = tid >> 6;
    const int w    = blockIdx.x * 4 + wv;
    const int row0 = w * 32;

    const f32x4 q0 = *reinterpret_cast<const f32x4*>(q + lane * 8);
    const f32x4 q1 = *reinterpret_cast<const f32x4*>(q + lane * 8 + 4);

    float m = -INFINITY, s = 0.f;   // per-lane online softmax state

    for (int b = 0; b < 4; ++b) {
        const int rb = row0 + b * 8;

        // per-lane partial distances for 8 rows (loads are independent ->
        // compiler software-pipelines them)
        float d[8];
        #pragma unroll
        for (int i = 0; i < 8; ++i) {
            const float* kp = keys + (size_t)(rb + i) * NF + lane * 8;
            const f32x4 k0 = __builtin_nontemporal_load(reinterpret_cast<const f32x4*>(kp));
            const f32x4 k1 = __builtin_nontemporal_load(reinterpret_cast<const f32x4*>(kp + 4));
            d[i] = fabsf(k0[0] - q0[0]) + fabsf(k0[1] - q0[1])
                 + fabsf(k0[2] - q0[2]) + fabsf(k0[3] - q0[3])
                 + fabsf(k1[0] - q1[0]) + fabsf(k1[1] - q1[1])
                 + fabsf(k1[2] - q1[2]) + fabsf(k1[3] - q1[3]);
        }

        // ---- batched reduction: 8 rows in 10 shfls ----
        // stage A (xor 1): pack row pairs; row bit0 <- lane bit0
        float p[4];
        #pragma unroll
        for (int i = 0; i < 4; ++i) {
            const float x = d[2 * i], y = d[2 * i + 1];
            const float keep = (lane & 1) ? y : x;
            const float send = (lane & 1) ? x : y;
            p[i] = keep + __shfl_xor(send, 1, 64);
        }
        // stage B (xor 2): row bit1 <- lane bit1
        float e[2];
        #pragma unroll
        for (int i = 0; i < 2; ++i) {
            const float x = p[2 * i], y = p[2 * i + 1];
            const float keep = (lane & 2) ? y : x;
            const float send = (lane & 2) ? x : y;
            e[i] = keep + __shfl_xor(send, 2, 64);
        }
        // stage C (xor 4): row bit2 <- lane bit2
        {
            const float keep = (lane & 4) ? e[1] : e[0];
            const float send = (lane & 4) ? e[0] : e[1];
            e[0] = keep + __shfl_xor(send, 4, 64);
        }
        // stages D-F: plain butterfly over remaining lane bits
        float r = e[0];
        r += __shfl_xor(r, 8, 64);
        r += __shfl_xor(r, 16, 64);
        r += __shfl_xor(r, 32, 64);

        const float L = -r;                 // logit of row rb + (lane & 7)
        if (lane < 8) logits[rb + lane] = L;

        // per-lane branchless online update (once per batch)
        const float Mn = fmaxf(m, L);
        s = s * __expf(m - Mn) + __expf(L - Mn);   // exp(-inf)=0 handles init
        m = Mn;
    }

    // Each row's contribution is replicated in 8 lanes (bit-identical);
    // scale by 1/8 (exact) so the 64-lane combine yields the true sum.
    s *= 0.125f;

    // combine (m,s) across the 64 lanes
    #pragma unroll
    for (int off = 1; off < 64; off <<= 1) {
        const float m2 = __shfl_xor(m, off, 64);
        const float s2 = __shfl_xor(s, off, 64);
        const float Mn = fmaxf(m, m2);
        s = s * __expf(m - Mn) + s2 * __expf(m2 - Mn);
        m = Mn;
    }

    __shared__ float sm[4], ss[4];
    if (lane == 0) { sm[wv] = m; ss[wv] = s; }
    __syncthreads();
    if (tid == 0) {
        float M = sm[0], S = ss[0];
        #pragma unroll
        for (int i = 1; i < 4; ++i) {
            const float Mn = fmaxf(M, sm[i]);
            S = S * __expf(M - Mn) + ss[i] * __expf(sm[i] - Mn);
            M = Mn;
        }
        pm[blockIdx.x] = M;
        ps[blockIdx.x] = S;
    }
}

// ---------------------------------------------------------------------------
// Kernel 2: combine G1 (m,s) partials -> scal[0]=global max, scal[1]=1/S.
// Single block, fixed-order (deterministic).
// ---------------------------------------------------------------------------
__global__ __launch_bounds__(256) void k_combine(
    const float* __restrict__ pm, const float* __restrict__ ps,
    float* __restrict__ scal, int n)
{
    const int tid = threadIdx.x;
    float M = -INFINITY, S = 0.f;
    for (int i = tid; i < n; i += 256) {
        const float m2 = pm[i], s2 = ps[i];
        const float Mn = fmaxf(M, m2);
        S = S * expf(M - Mn) + s2 * expf(m2 - Mn);
        M = Mn;
    }
    #pragma unroll
    for (int off = 1; off < 64; off <<= 1) {
        const float m2 = __shfl_xor(M, off, 64);
        const float s2 = __shfl_xor(S, off, 64);
        const float Mn = fmaxf(M, m2);
        S = S * expf(M - Mn) + s2 * expf(m2 - Mn);
        M = Mn;
    }
    __shared__ float sm[4], ss[4];
    const int lane = tid & 63, wv = tid >> 6;
    if (lane == 0) { sm[wv] = M; ss[wv] = S; }
    __syncthreads();
    if (tid == 0) {
        float Mg = sm[0], Sg = ss[0];
        #pragma unroll
        for (int i = 1; i < 4; ++i) {
            const float Mn = fmaxf(Mg, sm[i]);
            Sg = Sg * expf(Mg - Mn) + ss[i] * expf(sm[i] - Mn);
            Mg = Mn;
        }
        scal[0] = Mg;
        scal[1] = 1.f / Sg;
    }
}

// ---------------------------------------------------------------------------
// Kernel 3: per-block partial of out[o] = sum_r softmax[r] * values[r,o].
// 256 threads: 128 column-threads (f32x4 => 512 cols) x 2 row-groups.
// Pure streaming, no cross-lane ops -> runs at HBM BW.
// ---------------------------------------------------------------------------
__global__ __launch_bounds__(256) void k_wsum(
    const float* __restrict__ values, const float* __restrict__ logits,
    const float* __restrict__ scal, float* __restrict__ part)
{
    const int tid = threadIdx.x;
    const int col = (tid & 127) * 4;
    const int rg  = tid >> 7;
    const float m    = scal[0];
    const float invS = scal[1];

    const int r0 = blockIdx.x * (CAP / G3);   // 128 rows per block
    f32x4 acc = {0.f, 0.f, 0.f, 0.f};
    #pragma unroll 4
    for (int r = r0 + rg; r < r0 + (CAP / G3); r += 2) {
        const float wgt = __expf(logits[r] - m) * invS;
        const f32x4 v = __builtin_nontemporal_load(
            reinterpret_cast<const f32x4*>(values + (size_t)r * NF + col));
        acc += wgt * v;
    }

    __shared__ float sp[NF];
    if (rg == 0) *reinterpret_cast<f32x4*>(sp + col) = acc;
    __syncthreads();
    if (rg == 1) {
        sp[col + 0] += acc[0]; sp[col + 1] += acc[1];
        sp[col + 2] += acc[2]; sp[col + 3] += acc[3];
    }
    __syncthreads();
    if (rg == 0)
        *reinterpret_cast<f32x4*>(part + (size_t)blockIdx.x * NF + col) =
            *reinterpret_cast<const f32x4*>(sp + col);
}

// ---------------------------------------------------------------------------
// Kernel 4a: reduce G3 partial rows -> G4A rows (32:1), parallel across blocks.
// ---------------------------------------------------------------------------
__global__ __launch_bounds__(128) void k_red(
    const float* __restrict__ part, float* __restrict__ part2)
{
    const int tid = threadIdx.x;      // 0..127
    const int col = tid * 4;
    const size_t r0 = (size_t)blockIdx.x * (G3 / G4A);
    f32x4 acc = {0.f, 0.f, 0.f, 0.f};
    #pragma unroll 4
    for (int j = 0; j < (G3 / G4A); ++j) {
        const f32x4 v = *reinterpret_cast<const f32x4*>(part + (r0 + j) * NF + col);
        acc += v;
    }
    *reinterpret_cast<f32x4*>(part2 + (size_t)blockIdx.x * NF + col) = acc;
}

// ---------------------------------------------------------------------------
// Kernel 4b: reduce G4A rows -> out[512], apply sigmoid.
// ---------------------------------------------------------------------------
__global__ __launch_bounds__(256) void k_final(
    const float* __restrict__ part2, float* __restrict__ out)
{
    const int o = blockIdx.x * 256 + threadIdx.x;   // grid 2 x 256 = 512
    float acc = 0.f;
    #pragma unroll 8
    for (int j = 0; j < G4A; ++j) acc += part2[(size_t)j * NF + o];
    out[o] = 1.f / (1.f + expf(-acc));
}

// ---------------------------------------------------------------------------
extern "C" void kernel_launch(void* const* d_in, const int* in_sizes, int n_in,
                              void* d_out, int out_size, void* d_ws, size_t ws_size,
                              hipStream_t stream)
{
    const float* q    = (const float*)d_in[0];   // [512]
    const float* keys = (const float*)d_in[1];   // [262144, 512]
    const float* vals = (const float*)d_in[2];   // [262144, 512]
    float* out = (float*)d_out;                  // [512]

    // Workspace layout (floats). Total ~5.4 MB.
    float* ws     = (float*)d_ws;
    float* logits = ws;                          // CAP
    float* pm     = logits + CAP;                // G1
    float* ps     = pm + G1;                     // G1
    float* scal   = ps + G1;                     // 4 (padded for alignment)
    float* part   = scal + 4;                    // G3*NF (4 MB)
    float* part2  = part + (size_t)G3 * NF;      // G4A*NF (128 KB)

    k_logits <<<G1,  256, 0, stream>>>(q, keys, logits, pm, ps);
    k_combine<<<1,   256, 0, stream>>>(pm, ps, scal, G1);
    k_wsum   <<<G3,  256, 0, stream>>>(vals, logits, scal, part);
    k_red    <<<G4A, 128, 0, stream>>>(part, part2);
    k_final  <<<2,   256, 0, stream>>>(part2, out);
}

// Round 7
// 191.999 us; speedup vs baseline: 1.2754x; 1.0319x over previous
//
#include <hip/hip_runtime.h>
#include <math.h>

typedef float f32x4 __attribute__((ext_vector_type(4)));

// Problem constants (from reference setup_inputs)
constexpr int CAP = 262144;   // rows of keys/values
constexpr int NF  = 512;      // in_features == out_features

constexpr int GB  = 2048;     // fused blocks; 128 rows each, 4 waves x 32 rows
constexpr int RPB = CAP / GB; // 128 rows per block
constexpr int GR  = 64;       // k_red blocks
constexpr int RPR = GB / GR;  // 32 partial rows per red block

// ---------------------------------------------------------------------------
// Fused kernel: block b owns rows [b*128, b*128+128).
// Phase 1 (keys): 4 waves x 32 rows, batched butterfly (10 shfls / 8 rows);
//   logits stashed in LDS (never touch HBM); block-local online softmax
//   (m_b, s_b) via the x0.125 replication fix (proven in R6).
// Phase 2 (values): weight each of the block's 128 value rows by
//   exp(L - m_b) -- block-LOCAL max, so no dependency on any other block.
// Writes: partial[b][512] (unnormalized, local-max-scaled), pm[b]=m_b,
//   ps[b]=s_b. Global rescale happens in the tiny reduction kernels.
// ---------------------------------------------------------------------------
__global__ __launch_bounds__(256) void k_fused(
    const float* __restrict__ q, const float* __restrict__ keys,
    const float* __restrict__ vals,
    float* __restrict__ pm, float* __restrict__ ps, float* __restrict__ partial)
{
    const int tid  = threadIdx.x;
    const int lane = tid & 63;
    const int wv   = tid >> 6;

    __shared__ float lg[RPB];        // logits tile for this block's 128 rows
    __shared__ float sm[4], ss[4];   // per-wave (m, s)
    __shared__ float sp[NF];         // phase-2 column combine

    // ---------------- phase 1: keys ----------------
    const f32x4 q0 = *reinterpret_cast<const f32x4*>(q + lane * 8);
    const f32x4 q1 = *reinterpret_cast<const f32x4*>(q + lane * 8 + 4);

    float m = -INFINITY, s = 0.f;    // per-lane online softmax state
    const int row0 = blockIdx.x * RPB + wv * 32;

    for (int b = 0; b < 4; ++b) {
        const int rb = row0 + b * 8;

        float d[8];
        #pragma unroll
        for (int i = 0; i < 8; ++i) {
            const float* kp = keys + (size_t)(rb + i) * NF + lane * 8;
            const f32x4 k0 = __builtin_nontemporal_load(reinterpret_cast<const f32x4*>(kp));
            const f32x4 k1 = __builtin_nontemporal_load(reinterpret_cast<const f32x4*>(kp + 4));
            d[i] = fabsf(k0[0] - q0[0]) + fabsf(k0[1] - q0[1])
                 + fabsf(k0[2] - q0[2]) + fabsf(k0[3] - q0[3])
                 + fabsf(k1[0] - q1[0]) + fabsf(k1[1] - q1[1])
                 + fabsf(k1[2] - q1[2]) + fabsf(k1[3] - q1[3]);
        }

        // batched reduction: 8 rows in 10 shfls (row (lane&7) ends everywhere)
        float p[4];
        #pragma unroll
        for (int i = 0; i < 4; ++i) {
            const float x = d[2 * i], y = d[2 * i + 1];
            const float keep = (lane & 1) ? y : x;
            const float send = (lane & 1) ? x : y;
            p[i] = keep + __shfl_xor(send, 1, 64);
        }
        float e[2];
        #pragma unroll
        for (int i = 0; i < 2; ++i) {
            const float x = p[2 * i], y = p[2 * i + 1];
            const float keep = (lane & 2) ? y : x;
            const float send = (lane & 2) ? x : y;
            e[i] = keep + __shfl_xor(send, 2, 64);
        }
        {
            const float keep = (lane & 4) ? e[1] : e[0];
            const float send = (lane & 4) ? e[0] : e[1];
            e[0] = keep + __shfl_xor(send, 4, 64);
        }
        float r = e[0];
        r += __shfl_xor(r, 8, 64);
        r += __shfl_xor(r, 16, 64);
        r += __shfl_xor(r, 32, 64);

        const float L = -r;                       // logit of row rb + (lane&7)
        if (lane < 8) lg[wv * 32 + b * 8 + lane] = L;

        const float Mn = fmaxf(m, L);
        s = s * __expf(m - Mn) + __expf(L - Mn);  // exp(-inf)=0 handles init
        m = Mn;
    }

    // rows replicated in 8 lane-groups (bit-identical) -> exact 1/8 scale
    s *= 0.125f;
    #pragma unroll
    for (int off = 1; off < 64; off <<= 1) {
        const float m2 = __shfl_xor(m, off, 64);
        const float s2 = __shfl_xor(s, off, 64);
        const float Mn = fmaxf(m, m2);
        s = s * __expf(m - Mn) + s2 * __expf(m2 - Mn);
        m = Mn;
    }
    if (lane == 0) { sm[wv] = m; ss[wv] = s; }
    __syncthreads();   // publishes lg[], sm[], ss[]

    // block-local combine, redundantly in ALL threads (identical result)
    float mb = sm[0], sb = ss[0];
    #pragma unroll
    for (int i = 1; i < 4; ++i) {
        const float Mn = fmaxf(mb, sm[i]);
        sb = sb * __expf(mb - Mn) + ss[i] * __expf(sm[i] - Mn);
        mb = Mn;
    }

    // ---------------- phase 2: values ----------------
    const int col = (tid & 127) * 4;
    const int rg  = tid >> 7;
    const size_t gr0 = (size_t)blockIdx.x * RPB;

    f32x4 acc = {0.f, 0.f, 0.f, 0.f};
    #pragma unroll 4
    for (int r = rg; r < RPB; r += 2) {
        const float w = __expf(lg[r] - mb);       // local-max weight, <= 1
        const f32x4 v = __builtin_nontemporal_load(
            reinterpret_cast<const f32x4*>(vals + (gr0 + r) * NF + col));
        acc += w * v;
    }

    if (rg == 0) *reinterpret_cast<f32x4*>(sp + col) = acc;
    __syncthreads();
    if (rg == 1) {
        sp[col + 0] += acc[0]; sp[col + 1] += acc[1];
        sp[col + 2] += acc[2]; sp[col + 3] += acc[3];
    }
    __syncthreads();
    if (rg == 0)
        *reinterpret_cast<f32x4*>(partial + (size_t)blockIdx.x * NF + col) =
            *reinterpret_cast<const f32x4*>(sp + col);
    if (tid == 0) { pm[blockIdx.x] = mb; ps[blockIdx.x] = sb; }
}

// ---------------------------------------------------------------------------
// k_red: reduce GB partial rows -> GR rows, each scaled by exp(m_b - M).
// M computed inline per block from pm[GB] (8 KB, L2) -- pure fmax, exact and
// order-independent, so identical in every block.
// ---------------------------------------------------------------------------
__global__ __launch_bounds__(256) void k_red(
    const float* __restrict__ pm, const float* __restrict__ partial,
    float* __restrict__ part2)
{
    const int tid  = threadIdx.x;
    const int lane = tid & 63;
    const int wv   = tid >> 6;

    float mx = -INFINITY;
    for (int i = tid; i < GB; i += 256) mx = fmaxf(mx, pm[i]);
    #pragma unroll
    for (int off = 1; off < 64; off <<= 1) mx = fmaxf(mx, __shfl_xor(mx, off, 64));
    __shared__ float sm[4];
    if (lane == 0) sm[wv] = mx;
    __syncthreads();
    const float M = fmaxf(fmaxf(sm[0], sm[1]), fmaxf(sm[2], sm[3]));

    const int col = (tid & 127) * 4;
    const int rg  = tid >> 7;
    const int r0  = blockIdx.x * RPR;
    f32x4 acc = {0.f, 0.f, 0.f, 0.f};
    #pragma unroll 4
    for (int r = r0 + rg; r < r0 + RPR; r += 2) {
        const float sc = __expf(pm[r] - M);
        const f32x4 v = *reinterpret_cast<const f32x4*>(partial + (size_t)r * NF + col);
        acc += sc * v;
    }

    __shared__ float sp[NF];
    if (rg == 0) *reinterpret_cast<f32x4*>(sp + col) = acc;
    __syncthreads();
    if (rg == 1) {
        sp[col + 0] += acc[0]; sp[col + 1] += acc[1];
        sp[col + 2] += acc[2]; sp[col + 3] += acc[3];
    }
    __syncthreads();
    if (rg == 0)
        *reinterpret_cast<f32x4*>(part2 + (size_t)blockIdx.x * NF + col) =
            *reinterpret_cast<const f32x4*>(sp + col);
}

// ---------------------------------------------------------------------------
// k_final: M and S = sum_b s_b*exp(m_b-M) inline (deterministic, identical in
// both blocks); sum the GR partial rows; normalize; sigmoid.
// ---------------------------------------------------------------------------
__global__ __launch_bounds__(256) void k_final(
    const float* __restrict__ pm, const float* __restrict__ ps,
    const float* __restrict__ part2, float* __restrict__ out)
{
    const int tid  = threadIdx.x;
    const int lane = tid & 63;
    const int wv   = tid >> 6;

    float mx = -INFINITY;
    for (int i = tid; i < GB; i += 256) mx = fmaxf(mx, pm[i]);
    #pragma unroll
    for (int off = 1; off < 64; off <<= 1) mx = fmaxf(mx, __shfl_xor(mx, off, 64));
    __shared__ float sm[4], ss[4];
    if (lane == 0) sm[wv] = mx;
    __syncthreads();
    const float M = fmaxf(fmaxf(sm[0], sm[1]), fmaxf(sm[2], sm[3]));

    float sacc = 0.f;
    for (int i = tid; i < GB; i += 256) sacc += ps[i] * __expf(pm[i] - M);
    #pragma unroll
    for (int off = 1; off < 64; off <<= 1) sacc += __shfl_xor(sacc, off, 64);
    if (lane == 0) ss[wv] = sacc;
    __syncthreads();
    const float invS = 1.f / (ss[0] + ss[1] + ss[2] + ss[3]);

    const int o = blockIdx.x * 256 + tid;          // grid 2 x 256 = 512
    float acc = 0.f;
    #pragma unroll 8
    for (int j = 0; j < GR; ++j) acc += part2[(size_t)j * NF + o];
    out[o] = 1.f / (1.f + __expf(-acc * invS));
}

// ---------------------------------------------------------------------------
extern "C" void kernel_launch(void* const* d_in, const int* in_sizes, int n_in,
                              void* d_out, int out_size, void* d_ws, size_t ws_size,
                              hipStream_t stream)
{
    const float* q    = (const float*)d_in[0];   // [512]
    const float* keys = (const float*)d_in[1];   // [262144, 512]
    const float* vals = (const float*)d_in[2];   // [262144, 512]
    float* out = (float*)d_out;                  // [512]

    // Workspace layout (floats). Total ~4.2 MB.
    float* ws      = (float*)d_ws;
    float* pm      = ws;                         // GB
    float* ps      = pm + GB;                    // GB
    float* partial = ps + GB;                    // GB*NF (4 MB), 16B-aligned
    float* part2   = partial + (size_t)GB * NF;  // GR*NF (128 KB)

    k_fused<<<GB, 256, 0, stream>>>(q, keys, vals, pm, ps, partial);
    k_red  <<<GR, 256, 0, stream>>>(pm, partial, part2);
    k_final<<<2,  256, 0, stream>>>(pm, ps, part2, out);
}

// Round 8
// 185.075 us; speedup vs baseline: 1.3231x; 1.0374x over previous
//
#include <hip/hip_runtime.h>
#include <math.h>

typedef float f32x4 __attribute__((ext_vector_type(4)));

// Problem constants (from reference setup_inputs)
constexpr int CAP = 262144;   // rows of keys/values
constexpr int NF  = 512;      // in_features == out_features

constexpr int GB  = 2048;     // fused blocks; 128 rows each, 4 waves x 32 rows
constexpr int RPB = CAP / GB; // 128 rows per block
constexpr int GR  = 64;       // k_red blocks
constexpr int RPR = GB / GR;  // 32 partial rows per red block

// ---------------------------------------------------------------------------
// Single-pass fused kernel. Block b owns rows [b*128, b*128+128); each of the
// 4 waves owns 32 rows, processed as 8 batches of 4 rows:
//   1. issue the batch's 8 value loads (data-independent addresses) so they
//      overlap the key-load latency
//   2. 8 key loads -> per-lane partial L1 distances d[0..3]
//   3. batched butterfly, 7 shfls: lane j (j<4) ends with row j's full logit
//   4. broadcast the 4 logits to all lanes via __shfl(L, j) (v_readlane)
//   5. branchless online-softmax update of (m, s) and the 8-float/lane value
//      accumulator (always-rescale; exp(-inf)=0 makes batch 0 exact)
// No barrier anywhere in the loop; keys and values stream together.
// End: 4 waves combine (m, s, acc) via LDS with exact exp(m_w - m_b) rescale.
// Writes partial[b][512] (block-local-max scaled), pm[b]=m_b, ps[b]=s_b.
// ---------------------------------------------------------------------------
__global__ __launch_bounds__(256) void k_fused(
    const float* __restrict__ q, const float* __restrict__ keys,
    const float* __restrict__ vals,
    float* __restrict__ pm, float* __restrict__ ps, float* __restrict__ partial)
{
    const int tid  = threadIdx.x;
    const int lane = tid & 63;
    const int wv   = tid >> 6;

    __shared__ float sacc[4][NF];     // per-wave rescaled accumulators
    __shared__ float sms[4], sss[4];  // per-wave (m, s)

    // dense-coalesced column split: lane owns cols [lane*4, lane*4+4) and
    // [256+lane*4, 256+lane*4+4)  -> each dwordx4 covers a contiguous 1KB
    const int c0 = lane * 4;
    const int c1 = 256 + lane * 4;

    const f32x4 q0 = *reinterpret_cast<const f32x4*>(q + c0);
    const f32x4 q1 = *reinterpret_cast<const f32x4*>(q + c1);

    float m = -INFINITY, s = 0.f;
    f32x4 a0 = {0.f, 0.f, 0.f, 0.f};
    f32x4 a1 = {0.f, 0.f, 0.f, 0.f};

    const int row0 = blockIdx.x * RPB + wv * 32;

    for (int b = 0; b < 8; ++b) {
        const int rb = row0 + b * 4;
        const size_t base = (size_t)rb * NF;

        // ---- 1. issue value loads early ----
        f32x4 v0[4], v1[4];
        #pragma unroll
        for (int i = 0; i < 4; ++i) {
            const float* vp = vals + base + (size_t)i * NF;
            v0[i] = __builtin_nontemporal_load(reinterpret_cast<const f32x4*>(vp + c0));
            v1[i] = __builtin_nontemporal_load(reinterpret_cast<const f32x4*>(vp + c1));
        }

        // ---- 2. key loads + per-lane partial distances ----
        float d[4];
        #pragma unroll
        for (int i = 0; i < 4; ++i) {
            const float* kp = keys + base + (size_t)i * NF;
            const f32x4 k0 = __builtin_nontemporal_load(reinterpret_cast<const f32x4*>(kp + c0));
            const f32x4 k1 = __builtin_nontemporal_load(reinterpret_cast<const f32x4*>(kp + c1));
            d[i] = fabsf(k0[0] - q0[0]) + fabsf(k0[1] - q0[1])
                 + fabsf(k0[2] - q0[2]) + fabsf(k0[3] - q0[3])
                 + fabsf(k1[0] - q1[0]) + fabsf(k1[1] - q1[1])
                 + fabsf(k1[2] - q1[2]) + fabsf(k1[3] - q1[3]);
        }

        // ---- 3. batched butterfly: 4 rows in 7 shfls ----
        float p0, p1;
        {
            const float keep = (lane & 1) ? d[1] : d[0];
            const float send = (lane & 1) ? d[0] : d[1];
            p0 = keep + __shfl_xor(send, 1, 64);
        }
        {
            const float keep = (lane & 1) ? d[3] : d[2];
            const float send = (lane & 1) ? d[2] : d[3];
            p1 = keep + __shfl_xor(send, 1, 64);
        }
        float r;
        {
            const float keep = (lane & 2) ? p1 : p0;
            const float send = (lane & 2) ? p0 : p1;
            r = keep + __shfl_xor(send, 2, 64);
        }
        r += __shfl_xor(r, 4, 64);
        r += __shfl_xor(r, 8, 64);
        r += __shfl_xor(r, 16, 64);
        r += __shfl_xor(r, 32, 64);
        const float L = -r;                  // logit of row rb + (lane & 3)

        // ---- 4. broadcast the 4 row logits (readlane, wave-uniform) ----
        const float t0 = __shfl(L, 0, 64);
        const float t1 = __shfl(L, 1, 64);
        const float t2 = __shfl(L, 2, 64);
        const float t3 = __shfl(L, 3, 64);

        // ---- 5. online update (identical in every lane) ----
        const float bm   = fmaxf(fmaxf(t0, t1), fmaxf(t2, t3));
        const float Mn   = fmaxf(m, bm);
        const float resc = __expf(m - Mn);   // batch 0: exp(-inf) = 0
        const float e0 = __expf(t0 - Mn), e1 = __expf(t1 - Mn);
        const float e2 = __expf(t2 - Mn), e3 = __expf(t3 - Mn);
        s = s * resc + (e0 + e1 + e2 + e3);
        a0 = a0 * resc + e0 * v0[0] + e1 * v0[1] + e2 * v0[2] + e3 * v0[3];
        a1 = a1 * resc + e0 * v1[0] + e1 * v1[1] + e2 * v1[2] + e3 * v1[3];
        m = Mn;
    }

    // ---- block combine: 4 waves -> one partial row ----
    if (lane == 0) { sms[wv] = m; sss[wv] = s; }
    __syncthreads();
    float mb = fmaxf(fmaxf(sms[0], sms[1]), fmaxf(sms[2], sms[3]));
    float sb = sss[0] * __expf(sms[0] - mb) + sss[1] * __expf(sms[1] - mb)
             + sss[2] * __expf(sms[2] - mb) + sss[3] * __expf(sms[3] - mb);

    const float rs = __expf(m - mb);         // wave-uniform rescale to block max
    a0 *= rs; a1 *= rs;
    *reinterpret_cast<f32x4*>(&sacc[wv][c0]) = a0;
    *reinterpret_cast<f32x4*>(&sacc[wv][c1]) = a1;
    __syncthreads();

    const int c = tid * 2;                   // 256 threads x 2 cols = 512
    const float r0 = sacc[0][c]     + sacc[1][c]     + sacc[2][c]     + sacc[3][c];
    const float r1 = sacc[0][c + 1] + sacc[1][c + 1] + sacc[2][c + 1] + sacc[3][c + 1];
    float2 st = {r0, r1};
    *reinterpret_cast<float2*>(partial + (size_t)blockIdx.x * NF + c) = st;
    if (tid == 0) { pm[blockIdx.x] = mb; ps[blockIdx.x] = sb; }
}

// ---------------------------------------------------------------------------
// k_red: reduce GB partial rows -> GR rows, each scaled by exp(m_b - M).
// M computed inline per block from pm[GB] (8 KB, L2) -- pure fmax, exact and
// order-independent, so identical in every block.
// ---------------------------------------------------------------------------
__global__ __launch_bounds__(256) void k_red(
    const float* __restrict__ pm, const float* __restrict__ partial,
    float* __restrict__ part2)
{
    const int tid  = threadIdx.x;
    const int lane = tid & 63;
    const int wv   = tid >> 6;

    float mx = -INFINITY;
    for (int i = tid; i < GB; i += 256) mx = fmaxf(mx, pm[i]);
    #pragma unroll
    for (int off = 1; off < 64; off <<= 1) mx = fmaxf(mx, __shfl_xor(mx, off, 64));
    __shared__ float sm[4];
    if (lane == 0) sm[wv] = mx;
    __syncthreads();
    const float M = fmaxf(fmaxf(sm[0], sm[1]), fmaxf(sm[2], sm[3]));

    const int col = (tid & 127) * 4;
    const int rg  = tid >> 7;
    const int r0  = blockIdx.x * RPR;
    f32x4 acc = {0.f, 0.f, 0.f, 0.f};
    #pragma unroll 4
    for (int r = r0 + rg; r < r0 + RPR; r += 2) {
        const float sc = __expf(pm[r] - M);
        const f32x4 v = *reinterpret_cast<const f32x4*>(partial + (size_t)r * NF + col);
        acc += sc * v;
    }

    __shared__ float sp[NF];
    if (rg == 0) *reinterpret_cast<f32x4*>(sp + col) = acc;
    __syncthreads();
    if (rg == 1) {
        sp[col + 0] += acc[0]; sp[col + 1] += acc[1];
        sp[col + 2] += acc[2]; sp[col + 3] += acc[3];
    }
    __syncthreads();
    if (rg == 0)
        *reinterpret_cast<f32x4*>(part2 + (size_t)blockIdx.x * NF + col) =
            *reinterpret_cast<const f32x4*>(sp + col);
}

// ---------------------------------------------------------------------------
// k_final: M and S = sum_b s_b*exp(m_b-M) inline (deterministic, identical in
// both blocks); sum the GR partial rows; normalize; sigmoid.
// ---------------------------------------------------------------------------
__global__ __launch_bounds__(256) void k_final(
    const float* __restrict__ pm, const float* __restrict__ ps,
    const float* __restrict__ part2, float* __restrict__ out)
{
    const int tid  = threadIdx.x;
    const int lane = tid & 63;
    const int wv   = tid >> 6;

    float mx = -INFINITY;
    for (int i = tid; i < GB; i += 256) mx = fmaxf(mx, pm[i]);
    #pragma unroll
    for (int off = 1; off < 64; off <<= 1) mx = fmaxf(mx, __shfl_xor(mx, off, 64));
    __shared__ float sm[4], ss[4];
    if (lane == 0) sm[wv] = mx;
    __syncthreads();
    const float M = fmaxf(fmaxf(sm[0], sm[1]), fmaxf(sm[2], sm[3]));

    float sacc = 0.f;
    for (int i = tid; i < GB; i += 256) sacc += ps[i] * __expf(pm[i] - M);
    #pragma unroll
    for (int off = 1; off < 64; off <<= 1) sacc += __shfl_xor(sacc, off, 64);
    if (lane == 0) ss[wv] = sacc;
    __syncthreads();
    const float invS = 1.f / (ss[0] + ss[1] + ss[2] + ss[3]);

    const int o = blockIdx.x * 256 + tid;          // grid 2 x 256 = 512
    float acc = 0.f;
    #pragma unroll 8
    for (int j = 0; j < GR; ++j) acc += part2[(size_t)j * NF + o];
    out[o] = 1.f / (1.f + __expf(-acc * invS));
}

// ---------------------------------------------------------------------------
extern "C" void kernel_launch(void* const* d_in, const int* in_sizes, int n_in,
                              void* d_out, int out_size, void* d_ws, size_t ws_size,
                              hipStream_t stream)
{
    const float* q    = (const float*)d_in[0];   // [512]
    const float* keys = (const float*)d_in[1];   // [262144, 512]
    const float* vals = (const float*)d_in[2];   // [262144, 512]
    float* out = (float*)d_out;                  // [512]

    // Workspace layout (floats). Total ~4.2 MB.
    float* ws      = (float*)d_ws;
    float* pm      = ws;                         // GB
    float* ps      = pm + GB;                    // GB
    float* partial = ps + GB;                    // GB*NF (4 MB), 16B-aligned
    float* part2   = partial + (size_t)GB * NF;  // GR*NF (128 KB)

    k_fused<<<GB, 256, 0, stream>>>(q, keys, vals, pm, ps, partial);
    k_red  <<<GR, 256, 0, stream>>>(pm, partial, part2);
    k_final<<<2,  256, 0, stream>>>(pm, ps, part2, out);
}

// Round 9
// 125.124 us; speedup vs baseline: 1.9570x; 1.4791x over previous
//
#include <hip/hip_runtime.h>
#include <math.h>

typedef float f32x4 __attribute__((ext_vector_type(4)));

// Problem constants (from reference setup_inputs)
constexpr int CAP = 262144;   // rows of keys/values
constexpr int NF  = 512;      // in_features == out_features

constexpr int G1  = 2048;     // blocks; 128 rows each (4 waves x 32 rows)
constexpr int RPB = CAP / G1; // 128 rows per block
constexpr int GR  = 64;       // k_red blocks
constexpr int RPR = G1 / GR;  // 32 partial rows per red block

// Sparsity cutoff: rows with logit < M - CUT are dropped from the NUMERATOR
// only (denominator S stays exact). Worst-case bound: dropped mass
// <= 262144 * exp(-25) * max|v| ~ 2e-5 -> output shift <= 6e-6, vs
// threshold 1.9e-2. Deterministic predicate, same in k_wsum and k_red.
constexpr float CUT = 25.0f;

// ---------------------------------------------------------------------------
// Kernel 1 (keys, 512MB stream): logits[r] = -sum |keys[r,:] - q|, plus
// per-block (m_b = max logit, s_b = sum exp(L - m_b)). Proven R6 structure:
// one wave per 32 rows, batches of 8 rows, 10 shfls/batch; (m,s) replicated
// 8x across lane groups -> exact 0.125 rescale before the 64-lane combine.
// ---------------------------------------------------------------------------
__global__ __launch_bounds__(256) void k_logits(
    const float* __restrict__ q, const float* __restrict__ keys,
    float* __restrict__ logits, float* __restrict__ pm, float* __restrict__ ps)
{
    const int tid  = threadIdx.x;
    const int lane = tid & 63;
    const int wv   = tid >> 6;
    const int w    = blockIdx.x * 4 + wv;
    const int row0 = w * 32;

    const f32x4 q0 = *reinterpret_cast<const f32x4*>(q + lane * 8);
    const f32x4 q1 = *reinterpret_cast<const f32x4*>(q + lane * 8 + 4);

    float m = -INFINITY, s = 0.f;   // per-lane online softmax state

    for (int b = 0; b < 4; ++b) {
        const int rb = row0 + b * 8;

        float d[8];
        #pragma unroll
        for (int i = 0; i < 8; ++i) {
            const float* kp = keys + (size_t)(rb + i) * NF + lane * 8;
            const f32x4 k0 = __builtin_nontemporal_load(reinterpret_cast<const f32x4*>(kp));
            const f32x4 k1 = __builtin_nontemporal_load(reinterpret_cast<const f32x4*>(kp + 4));
            d[i] = fabsf(k0[0] - q0[0]) + fabsf(k0[1] - q0[1])
                 + fabsf(k0[2] - q0[2]) + fabsf(k0[3] - q0[3])
                 + fabsf(k1[0] - q1[0]) + fabsf(k1[1] - q1[1])
                 + fabsf(k1[2] - q1[2]) + fabsf(k1[3] - q1[3]);
        }

        // batched reduction: 8 rows in 10 shfls (lane l&7 ends with row l&7)
        float p[4];
        #pragma unroll
        for (int i = 0; i < 4; ++i) {
            const float x = d[2 * i], y = d[2 * i + 1];
            const float keep = (lane & 1) ? y : x;
            const float send = (lane & 1) ? x : y;
            p[i] = keep + __shfl_xor(send, 1, 64);
        }
        float e[2];
        #pragma unroll
        for (int i = 0; i < 2; ++i) {
            const float x = p[2 * i], y = p[2 * i + 1];
            const float keep = (lane & 2) ? y : x;
            const float send = (lane & 2) ? x : y;
            e[i] = keep + __shfl_xor(send, 2, 64);
        }
        {
            const float keep = (lane & 4) ? e[1] : e[0];
            const float send = (lane & 4) ? e[0] : e[1];
            e[0] = keep + __shfl_xor(send, 4, 64);
        }
        float r = e[0];
        r += __shfl_xor(r, 8, 64);
        r += __shfl_xor(r, 16, 64);
        r += __shfl_xor(r, 32, 64);

        const float L = -r;                 // logit of row rb + (lane & 7)
        if (lane < 8) logits[rb + lane] = L;

        const float Mn = fmaxf(m, L);
        s = s * __expf(m - Mn) + __expf(L - Mn);   // exp(-inf)=0 handles init
        m = Mn;
    }

    // rows replicated in 8 lane-groups (bit-identical) -> exact 1/8 scale
    s *= 0.125f;
    #pragma unroll
    for (int off = 1; off < 64; off <<= 1) {
        const float m2 = __shfl_xor(m, off, 64);
        const float s2 = __shfl_xor(s, off, 64);
        const float Mn = fmaxf(m, m2);
        s = s * __expf(m - Mn) + s2 * __expf(m2 - Mn);
        m = Mn;
    }

    __shared__ float sm[4], ss[4];
    if (lane == 0) { sm[wv] = m; ss[wv] = s; }
    __syncthreads();
    if (tid == 0) {
        float M = sm[0], S = ss[0];
        #pragma unroll
        for (int i = 1; i < 4; ++i) {
            const float Mn = fmaxf(M, sm[i]);
            S = S * __expf(M - Mn) + ss[i] * __expf(sm[i] - Mn);
            M = Mn;
        }
        pm[blockIdx.x] = M;
        ps[blockIdx.x] = S;
    }
}

// ---------------------------------------------------------------------------
// Kernel 2: combine G1 (m,s) partials -> scal[0]=global max M, scal[1]=1/S.
// Single block, fixed order (deterministic). M is an exact fmax -> identical
// to any other exact-max recomputation.
// ---------------------------------------------------------------------------
__global__ __launch_bounds__(256) void k_combine(
    const float* __restrict__ pm, const float* __restrict__ ps,
    float* __restrict__ scal)
{
    const int tid = threadIdx.x;
    float M = -INFINITY, S = 0.f;
    for (int i = tid; i < G1; i += 256) {
        const float m2 = pm[i], s2 = ps[i];
        const float Mn = fmaxf(M, m2);
        S = S * __expf(M - Mn) + s2 * __expf(m2 - Mn);
        M = Mn;
    }
    #pragma unroll
    for (int off = 1; off < 64; off <<= 1) {
        const float m2 = __shfl_xor(M, off, 64);
        const float s2 = __shfl_xor(S, off, 64);
        const float Mn = fmaxf(M, m2);
        S = S * __expf(M - Mn) + s2 * __expf(m2 - Mn);
        M = Mn;
    }
    __shared__ float sm[4], ss[4];
    const int lane = tid & 63, wv = tid >> 6;
    if (lane == 0) { sm[wv] = M; ss[wv] = S; }
    __syncthreads();
    if (tid == 0) {
        float Mg = sm[0], Sg = ss[0];
        #pragma unroll
        for (int i = 1; i < 4; ++i) {
            const float Mn = fmaxf(Mg, sm[i]);
            Sg = Sg * __expf(Mg - Mn) + ss[i] * __expf(sm[i] - Mn);
            Mg = Mn;
        }
        scal[0] = Mg;
        scal[1] = 1.f / Sg;
    }
}

// ---------------------------------------------------------------------------
// Kernel 3 (SPARSE value pass): block b exits instantly unless its max logit
// pm[b] >= M - CUT. Surviving blocks stream only rows with logit >= M - CUT
// (block-half-uniform branch; each subgroup reads the same logits[r]).
// partial[b] = sum_kept exp(L - pm[b]) * v_row  (local-max scaled, <= 1).
// Unwritten partial rows are never read (k_red uses the same predicate).
// ---------------------------------------------------------------------------
__global__ __launch_bounds__(256) void k_wsum_sparse(
    const float* __restrict__ vals, const float* __restrict__ logits,
    const float* __restrict__ pm, const float* __restrict__ scal,
    float* __restrict__ partial)
{
    const float M  = scal[0];
    const float mb = pm[blockIdx.x];
    if (mb < M - CUT) return;                 // block-uniform early exit

    const int tid = threadIdx.x;
    const int col = (tid & 127) * 4;
    const int rg  = tid >> 7;
    const size_t gr0 = (size_t)blockIdx.x * RPB;

    f32x4 acc = {0.f, 0.f, 0.f, 0.f};
    for (int r = rg; r < RPB; r += 2) {
        const float L = logits[gr0 + r];      // same addr across subgroup
        if (L < M - CUT) continue;            // subgroup-uniform skip
        const float w = __expf(L - mb);
        const f32x4 v = *reinterpret_cast<const f32x4*>(vals + (gr0 + r) * NF + col);
        acc += w * v;
    }

    __shared__ float sp[NF];
    if (rg == 0) *reinterpret_cast<f32x4*>(sp + col) = acc;
    __syncthreads();
    if (rg == 1) {
        sp[col + 0] += acc[0]; sp[col + 1] += acc[1];
        sp[col + 2] += acc[2]; sp[col + 3] += acc[3];
    }
    __syncthreads();
    if (rg == 0)
        *reinterpret_cast<f32x4*>(partial + (size_t)blockIdx.x * NF + col) =
            *reinterpret_cast<const f32x4*>(sp + col);
}

// ---------------------------------------------------------------------------
// Kernel 4: reduce valid partial rows -> GR rows, scaled by exp(pm[r] - M).
// Same validity predicate as k_wsum_sparse -> reads only written rows.
// Always writes its part2 row (zeros if nothing valid).
// ---------------------------------------------------------------------------
__global__ __launch_bounds__(256) void k_red(
    const float* __restrict__ pm, const float* __restrict__ scal,
    const float* __restrict__ partial, float* __restrict__ part2)
{
    const float M = scal[0];
    const int tid = threadIdx.x;
    const int col = (tid & 127) * 4;
    const int rg  = tid >> 7;
    const int r0  = blockIdx.x * RPR;

    f32x4 acc = {0.f, 0.f, 0.f, 0.f};
    for (int r = r0 + rg; r < r0 + RPR; r += 2) {
        const float mbr = pm[r];
        if (mbr < M - CUT) continue;          // skip never-written rows
        const float sc = __expf(mbr - M);
        const f32x4 v = *reinterpret_cast<const f32x4*>(partial + (size_t)r * NF + col);
        acc += sc * v;
    }

    __shared__ float sp[NF];
    if (rg == 0) *reinterpret_cast<f32x4*>(sp + col) = acc;
    __syncthreads();
    if (rg == 1) {
        sp[col + 0] += acc[0]; sp[col + 1] += acc[1];
        sp[col + 2] += acc[2]; sp[col + 3] += acc[3];
    }
    __syncthreads();
    if (rg == 0)
        *reinterpret_cast<f32x4*>(part2 + (size_t)blockIdx.x * NF + col) =
            *reinterpret_cast<const f32x4*>(sp + col);
}

// ---------------------------------------------------------------------------
// Kernel 5: final. Recompute M (exact max) and S from pm/ps (deterministic,
// identical in both blocks); sum GR partial rows; normalize; sigmoid.
// ---------------------------------------------------------------------------
__global__ __launch_bounds__(256) void k_final(
    const float* __restrict__ pm, const float* __restrict__ ps,
    const float* __restrict__ part2, float* __restrict__ out)
{
    const int tid  = threadIdx.x;
    const int lane = tid & 63;
    const int wv   = tid >> 6;

    float mx = -INFINITY;
    for (int i = tid; i < G1; i += 256) mx = fmaxf(mx, pm[i]);
    #pragma unroll
    for (int off = 1; off < 64; off <<= 1) mx = fmaxf(mx, __shfl_xor(mx, off, 64));
    __shared__ float sm[4], ss[4];
    if (lane == 0) sm[wv] = mx;
    __syncthreads();
    const float M = fmaxf(fmaxf(sm[0], sm[1]), fmaxf(sm[2], sm[3]));

    float sacc = 0.f;
    for (int i = tid; i < G1; i += 256) sacc += ps[i] * __expf(pm[i] - M);
    #pragma unroll
    for (int off = 1; off < 64; off <<= 1) sacc += __shfl_xor(sacc, off, 64);
    if (lane == 0) ss[wv] = sacc;
    __syncthreads();
    const float invS = 1.f / (ss[0] + ss[1] + ss[2] + ss[3]);

    const int o = blockIdx.x * 256 + tid;          // grid 2 x 256 = 512
    float acc = 0.f;
    #pragma unroll 8
    for (int j = 0; j < GR; ++j) acc += part2[(size_t)j * NF + o];
    out[o] = 1.f / (1.f + __expf(-acc * invS));
}

// ---------------------------------------------------------------------------
extern "C" void kernel_launch(void* const* d_in, const int* in_sizes, int n_in,
                              void* d_out, int out_size, void* d_ws, size_t ws_size,
                              hipStream_t stream)
{
    const float* q    = (const float*)d_in[0];   // [512]
    const float* keys = (const float*)d_in[1];   // [262144, 512]
    const float* vals = (const float*)d_in[2];   // [262144, 512]
    float* out = (float*)d_out;                  // [512]

    // Workspace layout (floats). Total ~5.4 MB.
    float* ws      = (float*)d_ws;
    float* logits  = ws;                         // CAP
    float* pm      = logits + CAP;               // G1
    float* ps      = pm + G1;                    // G1
    float* scal    = ps + G1;                    // 4 (alignment pad)
    float* partial = scal + 4;                   // G1*NF (4 MB)
    float* part2   = partial + (size_t)G1 * NF;  // GR*NF (128 KB)

    k_logits     <<<G1, 256, 0, stream>>>(q, keys, logits, pm, ps);
    k_combine    <<<1,  256, 0, stream>>>(pm, ps, scal);
    k_wsum_sparse<<<G1, 256, 0, stream>>>(vals, logits, pm, scal, partial);
    k_red        <<<GR, 256, 0, stream>>>(pm, scal, partial, part2);
    k_final      <<<2,  256, 0, stream>>>(pm, ps, part2, out);
}

// Round 10
// 117.592 us; speedup vs baseline: 2.0823x; 1.0641x over previous
//
#include <hip/hip_runtime.h>
#include <math.h>

typedef float f32x4 __attribute__((ext_vector_type(4)));

// Problem constants (from reference setup_inputs)
constexpr int CAP = 262144;   // rows of keys/values
constexpr int NF  = 512;      // in_features == out_features

constexpr int G1  = 2048;     // blocks; 128 rows each (4 waves x 32 rows)
constexpr int RPB = CAP / G1; // 128 rows per block
constexpr int GR  = 64;       // k_red blocks
constexpr int RPR = G1 / GR;  // 32 partial rows per red block

// Sparsity cutoff: rows with logit < M - CUT are dropped from the NUMERATOR
// only (denominator S stays exact). Worst-case: dropped mass <=
// 262144*exp(-25)*max|v| ~ 2e-5 -> output shift <= 6e-6 << 1.9e-2 threshold.
// Deterministic predicate, identical in producer and consumers.
constexpr float CUT = 25.0f;

// ---------------------------------------------------------------------------
// helpers for k_logits: load 8 rows (2 f32x4/lane each), L1-distance vs q
// ---------------------------------------------------------------------------
__device__ __forceinline__ void load8(const float* __restrict__ keys, int rb,
                                      int lane, f32x4* K0, f32x4* K1)
{
    #pragma unroll
    for (int i = 0; i < 8; ++i) {
        const float* kp = keys + (size_t)(rb + i) * NF + lane * 8;
        K0[i] = __builtin_nontemporal_load(reinterpret_cast<const f32x4*>(kp));
        K1[i] = __builtin_nontemporal_load(reinterpret_cast<const f32x4*>(kp + 4));
    }
}

__device__ __forceinline__ float dist2(const f32x4 k0, const f32x4 k1,
                                       const f32x4 q0, const f32x4 q1)
{
    return fabsf(k0[0] - q0[0]) + fabsf(k0[1] - q0[1])
         + fabsf(k0[2] - q0[2]) + fabsf(k0[3] - q0[3])
         + fabsf(k1[0] - q1[0]) + fabsf(k1[1] - q1[1])
         + fabsf(k1[2] - q1[2]) + fabsf(k1[3] - q1[3]);
}

// ---------------------------------------------------------------------------
// Kernel 1 (keys, 512MB stream): logits[r] = -sum |keys[r,:] - q|, plus
// per-block (m_b, s_b). One wave per 32 rows, batches of 8 rows with the
// proven 10-shfl batched butterfly. NEW: register prefetch — batch b+1's 16
// loads are issued BEFORE batch b's butterfly, so the ~300-cycle shfl/exp
// serial tail overlaps HBM latency instead of draining the pipe.
// ---------------------------------------------------------------------------
__global__ __launch_bounds__(256) void k_logits(
    const float* __restrict__ q, const float* __restrict__ keys,
    float* __restrict__ logits, float* __restrict__ pm, float* __restrict__ ps)
{
    const int tid  = threadIdx.x;
    const int lane = tid & 63;
    const int wv   = tid >> 6;
    const int w    = blockIdx.x * 4 + wv;
    const int row0 = w * 32;

    const f32x4 q0 = *reinterpret_cast<const f32x4*>(q + lane * 8);
    const f32x4 q1 = *reinterpret_cast<const f32x4*>(q + lane * 8 + 4);

    float m = -INFINITY, s = 0.f;   // per-lane online softmax state

    f32x4 K0[8], K1[8];
    load8(keys, row0, lane, K0, K1);

    #pragma unroll
    for (int b = 0; b < 4; ++b) {
        const int rb = row0 + b * 8;

        // consume current batch -> per-lane partial distances
        float d[8];
        #pragma unroll
        for (int i = 0; i < 8; ++i) d[i] = dist2(K0[i], K1[i], q0, q1);

        // prefetch next batch (issued before the serial butterfly tail)
        if (b < 3) load8(keys, rb + 8, lane, K0, K1);

        // batched reduction: 8 rows in 10 shfls (lane l ends with row l&7)
        float p[4];
        #pragma unroll
        for (int i = 0; i < 4; ++i) {
            const float x = d[2 * i], y = d[2 * i + 1];
            const float keep = (lane & 1) ? y : x;
            const float send = (lane & 1) ? x : y;
            p[i] = keep + __shfl_xor(send, 1, 64);
        }
        float e[2];
        #pragma unroll
        for (int i = 0; i < 2; ++i) {
            const float x = p[2 * i], y = p[2 * i + 1];
            const float keep = (lane & 2) ? y : x;
            const float send = (lane & 2) ? x : y;
            e[i] = keep + __shfl_xor(send, 2, 64);
        }
        {
            const float keep = (lane & 4) ? e[1] : e[0];
            const float send = (lane & 4) ? e[0] : e[1];
            e[0] = keep + __shfl_xor(send, 4, 64);
        }
        float r = e[0];
        r += __shfl_xor(r, 8, 64);
        r += __shfl_xor(r, 16, 64);
        r += __shfl_xor(r, 32, 64);

        const float L = -r;                 // logit of row rb + (lane & 7)
        if (lane < 8) logits[rb + lane] = L;

        const float Mn = fmaxf(m, L);
        s = s * __expf(m - Mn) + __expf(L - Mn);   // exp(-inf)=0 handles init
        m = Mn;
    }

    // rows replicated in 8 lane-groups (bit-identical) -> exact 1/8 scale
    s *= 0.125f;
    #pragma unroll
    for (int off = 1; off < 64; off <<= 1) {
        const float m2 = __shfl_xor(m, off, 64);
        const float s2 = __shfl_xor(s, off, 64);
        const float Mn = fmaxf(m, m2);
        s = s * __expf(m - Mn) + s2 * __expf(m2 - Mn);
        m = Mn;
    }

    __shared__ float sm[4], ss[4];
    if (lane == 0) { sm[wv] = m; ss[wv] = s; }
    __syncthreads();
    if (tid == 0) {
        float M = sm[0], S = ss[0];
        #pragma unroll
        for (int i = 1; i < 4; ++i) {
            const float Mn = fmaxf(M, sm[i]);
            S = S * __expf(M - Mn) + ss[i] * __expf(sm[i] - Mn);
            M = Mn;
        }
        pm[blockIdx.x] = M;
        ps[blockIdx.x] = S;
    }
}

// ---------------------------------------------------------------------------
// inline global-max helper: exact fmax scan of pm[G1] (8KB, L2-resident).
// Order-independent -> bit-identical in every block of every kernel.
// Uses one __syncthreads; call before any divergent exit.
// ---------------------------------------------------------------------------
__device__ __forceinline__ float global_max(const float* __restrict__ pm,
                                            int tid, int lane, int wv)
{
    float mx = -INFINITY;
    for (int i = tid; i < G1; i += 256) mx = fmaxf(mx, pm[i]);
    #pragma unroll
    for (int off = 1; off < 64; off <<= 1) mx = fmaxf(mx, __shfl_xor(mx, off, 64));
    __shared__ float smx[4];
    if (lane == 0) smx[wv] = mx;
    __syncthreads();
    return fmaxf(fmaxf(smx[0], smx[1]), fmaxf(smx[2], smx[3]));
}

// ---------------------------------------------------------------------------
// Kernel 2 (SPARSE value pass): M computed inline (no k_combine). Block b
// exits unless pm[b] >= M - CUT; surviving blocks stream only rows with
// logit >= M - CUT. partial[b] = sum_kept exp(L - pm[b]) * v_row.
// Unwritten partial rows are never read (k_red uses the same predicate).
// ---------------------------------------------------------------------------
__global__ __launch_bounds__(256) void k_wsum_sparse(
    const float* __restrict__ vals, const float* __restrict__ logits,
    const float* __restrict__ pm, float* __restrict__ partial)
{
    const int tid  = threadIdx.x;
    const int lane = tid & 63;
    const int wv   = tid >> 6;

    const float M  = global_max(pm, tid, lane, wv);   // contains __syncthreads
    const float mb = pm[blockIdx.x];
    if (mb < M - CUT) return;                 // block-uniform early exit

    const int col = (tid & 127) * 4;
    const int rg  = tid >> 7;
    const size_t gr0 = (size_t)blockIdx.x * RPB;

    f32x4 acc = {0.f, 0.f, 0.f, 0.f};
    for (int r = rg; r < RPB; r += 2) {
        const float L = logits[gr0 + r];      // same addr across subgroup
        if (L < M - CUT) continue;            // subgroup-uniform skip
        const float w = __expf(L - mb);
        const f32x4 v = *reinterpret_cast<const f32x4*>(vals + (gr0 + r) * NF + col);
        acc += w * v;
    }

    __shared__ float sp[NF];
    if (rg == 0) *reinterpret_cast<f32x4*>(sp + col) = acc;
    __syncthreads();
    if (rg == 1) {
        sp[col + 0] += acc[0]; sp[col + 1] += acc[1];
        sp[col + 2] += acc[2]; sp[col + 3] += acc[3];
    }
    __syncthreads();
    if (rg == 0)
        *reinterpret_cast<f32x4*>(partial + (size_t)blockIdx.x * NF + col) =
            *reinterpret_cast<const f32x4*>(sp + col);
}

// ---------------------------------------------------------------------------
// Kernel 3: reduce valid partial rows -> GR rows, scaled by exp(pm[r] - M).
// M inline; same validity predicate -> reads only written rows. Always
// writes its part2 row (zeros if nothing valid).
// ---------------------------------------------------------------------------
__global__ __launch_bounds__(256) void k_red(
    const float* __restrict__ pm, const float* __restrict__ partial,
    float* __restrict__ part2)
{
    const int tid  = threadIdx.x;
    const int lane = tid & 63;
    const int wv   = tid >> 6;

    const float M = global_max(pm, tid, lane, wv);

    const int col = (tid & 127) * 4;
    const int rg  = tid >> 7;
    const int r0  = blockIdx.x * RPR;

    f32x4 acc = {0.f, 0.f, 0.f, 0.f};
    for (int r = r0 + rg; r < r0 + RPR; r += 2) {
        const float mbr = pm[r];
        if (mbr < M - CUT) continue;          // skip never-written rows
        const float sc = __expf(mbr - M);
        const f32x4 v = *reinterpret_cast<const f32x4*>(partial + (size_t)r * NF + col);
        acc += sc * v;
    }

    __shared__ float sp[NF];
    if (rg == 0) *reinterpret_cast<f32x4*>(sp + col) = acc;
    __syncthreads();
    if (rg == 1) {
        sp[col + 0] += acc[0]; sp[col + 1] += acc[1];
        sp[col + 2] += acc[2]; sp[col + 3] += acc[3];
    }
    __syncthreads();
    if (rg == 0)
        *reinterpret_cast<f32x4*>(part2 + (size_t)blockIdx.x * NF + col) =
            *reinterpret_cast<const f32x4*>(sp + col);
}

// ---------------------------------------------------------------------------
// Kernel 4: final. M and S = sum_b s_b*exp(m_b-M) inline (deterministic,
// identical in both blocks); sum GR partial rows; normalize; sigmoid.
// ---------------------------------------------------------------------------
__global__ __launch_bounds__(256) void k_final(
    const float* __restrict__ pm, const float* __restrict__ ps,
    const float* __restrict__ part2, float* __restrict__ out)
{
    const int tid  = threadIdx.x;
    const int lane = tid & 63;
    const int wv   = tid >> 6;

    const float M = global_max(pm, tid, lane, wv);

    float sacc = 0.f;
    for (int i = tid; i < G1; i += 256) sacc += ps[i] * __expf(pm[i] - M);
    #pragma unroll
    for (int off = 1; off < 64; off <<= 1) sacc += __shfl_xor(sacc, off, 64);
    __shared__ float ss[4];
    if (lane == 0) ss[wv] = sacc;
    __syncthreads();
    const float invS = 1.f / (ss[0] + ss[1] + ss[2] + ss[3]);

    const int o = blockIdx.x * 256 + tid;          // grid 2 x 256 = 512
    float acc = 0.f;
    #pragma unroll 8
    for (int j = 0; j < GR; ++j) acc += part2[(size_t)j * NF + o];
    out[o] = 1.f / (1.f + __expf(-acc * invS));
}

// ---------------------------------------------------------------------------
extern "C" void kernel_launch(void* const* d_in, const int* in_sizes, int n_in,
                              void* d_out, int out_size, void* d_ws, size_t ws_size,
                              hipStream_t stream)
{
    const float* q    = (const float*)d_in[0];   // [512]
    const float* keys = (const float*)d_in[1];   // [262144, 512]
    const float* vals = (const float*)d_in[2];   // [262144, 512]
    float* out = (float*)d_out;                  // [512]

    // Workspace layout (floats). Total ~5.4 MB.
    float* ws      = (float*)d_ws;
    float* logits  = ws;                         // CAP
    float* pm      = logits + CAP;               // G1
    float* ps      = pm + G1;                    // G1 (+pad to 16B)
    float* partial = ps + G1;                    // G1*NF (4 MB)
    float* part2   = partial + (size_t)G1 * NF;  // GR*NF (128 KB)

    k_logits     <<<G1, 256, 0, stream>>>(q, keys, logits, pm, ps);
    k_wsum_sparse<<<G1, 256, 0, stream>>>(vals, logits, pm, partial);
    k_red        <<<GR, 256, 0, stream>>>(pm, partial, part2);
    k_final      <<<2,  256, 0, stream>>>(pm, ps, part2, out);
}